// Round 9
// baseline (403.578 us; speedup 1.0000x reference)
//
#include <hip/hip_runtime.h>
#include <cmath>

typedef _Float16 half8 __attribute__((ext_vector_type(8)));
typedef float f32x4 __attribute__((ext_vector_type(4)));

constexpr int N = 16384;   // rows
constexpr int D = 256;     // half feature dim
constexpr int K = 512;     // 2D
constexpr int V = 8192;    // codebook size
// fp16 score error: std = 2*sqrt(2)*2^-12*||z.w||_2 ~ 4.9e-4; 12-sigma + accum
// slack -> per-code bound B ~ 6e-3. TAU >= 2B keeps fixup set a superset of
// the exact argmin. (R7's 0.05 was a worst-case bound; this is the stochastic one.)
constexpr float TAU = 0.015f;

#define GLOAD16(g, l) __builtin_amdgcn_global_load_lds(                     \
    (const __attribute__((address_space(1))) void*)(g),                    \
    (__attribute__((address_space(3))) void*)(l), 16, 0, 0)

// --------------------------- convert z (concat real|imag) to fp16 [N][K]
__global__ __launch_bounds__(256) void vq_cvt_z(
    const float* __restrict__ zr, const float* __restrict__ zi,
    _Float16* __restrict__ Zf) {
  int t = blockIdx.x * 256 + threadIdx.x;   // [0, N*64)
  int n = t >> 6, c8 = t & 63, k = c8 * 8;
  const float* src = (k < D) ? zr + (size_t)n * D + k : zi + (size_t)n * D + (k - D);
  float4 a = *(const float4*)src;
  float4 b = *(const float4*)(src + 4);
  half8 h;
  h[0] = (_Float16)a.x; h[1] = (_Float16)a.y; h[2] = (_Float16)a.z; h[3] = (_Float16)a.w;
  h[4] = (_Float16)b.x; h[5] = (_Float16)b.y; h[6] = (_Float16)b.z; h[7] = (_Float16)b.w;
  *(half8*)&Zf[(size_t)n * K + k] = h;
}

// ------------------------------------------------------ convert w to fp16
__global__ __launch_bounds__(256) void vq_cvt_w(
    const float* __restrict__ w, _Float16* __restrict__ Wf) {
  int t = blockIdx.x * 256 + threadIdx.x;   // [0, V*64)
  int vrow = t >> 6, c8 = t & 63, k = c8 * 8;
  const float* src = w + (size_t)vrow * K + k;
  float4 a = *(const float4*)src;
  float4 b = *(const float4*)(src + 4);
  half8 h;
  h[0] = (_Float16)a.x; h[1] = (_Float16)a.y; h[2] = (_Float16)a.z; h[3] = (_Float16)a.w;
  h[4] = (_Float16)b.x; h[5] = (_Float16)b.y; h[6] = (_Float16)b.z; h[7] = (_Float16)b.w;
  *(half8*)&Wf[(size_t)vrow * K + k] = h;
}

// ---------------------------------------------------------------- w2 = ||w||^2
__global__ __launch_bounds__(256) void vq_w2(const float* __restrict__ w,
                                             double* __restrict__ w2d,
                                             float* __restrict__ w2f) {
  int v = blockIdx.x * 4 + (threadIdx.x >> 6);
  int lane = threadIdx.x & 63;
  const float4* wr = (const float4*)(w + (size_t)v * K);
  float4 a = wr[lane];
  float4 b = wr[64 + lane];
  double s = (double)a.x * a.x + (double)a.y * a.y + (double)a.z * a.z + (double)a.w * a.w +
             (double)b.x * b.x + (double)b.y * b.y + (double)b.z * b.z + (double)b.w * b.w;
#pragma unroll
  for (int off = 1; off < 64; off <<= 1) s += __shfl_xor(s, off, 64);
  if (lane == 0) { w2d[v] = s; w2f[v] = (float)s; }
}

// ------ pass 1: fp16 MFMA GEMM, flash-style: block sweeps 4 v-tiles (512 cols)
// keeping per-lane top-2 in registers; one shuffle-epilogue per block.
// grid 2048: nt = bid >> 4 (N/128), vtg = bid & 15 (V/512). 256 thr = 4 waves 2x2.
__global__ __launch_bounds__(256) void vq_pass1(
    const _Float16* __restrict__ Zf, const _Float16* __restrict__ Wf,
    const float* __restrict__ w2f,
    float* __restrict__ pm1, float* __restrict__ pm2, int* __restrict__ pi1) {
  // per buffer: Z tile [128][32] + W tile [128][32] fp16 = 16 KiB; 3 bufs = 48 KiB
  __shared__ __align__(16) unsigned short smem[3][8192];
  __shared__ float w2lds[512];

  const int tid = threadIdx.x;
  const int w = tid >> 6, lane = tid & 63;
  const int wr = w >> 1, wc = w & 1;
  const int tx = lane & 15, g = lane >> 4;
  const int rsub = lane >> 2, kq = lane & 3;     // staging row-sub / k-quad
  const int nt = blockIdx.x >> 4, vtg = blockIdx.x & 15;
  const int rowBase = nt * 128, colBase = vtg * 512;

  // stage w2 for this block's 512 cols into LDS (keeps vmcnt bookkeeping clean)
  w2lds[tid] = w2f[colBase + tid];
  w2lds[256 + tid] = w2f[colBase + 256 + tid];

  // running per-lane top-2 per (m,r): 16 rows x (m1,m2,i1)
  float tm1[4][4], tm2[4][4];
  int ti1[4][4];
#pragma unroll
  for (int m = 0; m < 4; ++m)
#pragma unroll
    for (int r = 0; r < 4; ++r) { tm1[m][r] = 3.4e38f; tm2[m][r] = 3.4e38f; ti1[m][r] = 0x7fffffff; }

  const int sst = (rsub >> 1) & 3;  // stage-side swizzle (pre-swizzled global src)
  const int srd = (tx >> 1) & 3;    // read-side swizzle (same involution)

  // staging: 8 chunks of 16 rows; chunk c handled by wave c>>1, half c&1
  const int c0 = 2 * w, c1 = 2 * w + 1;
  const int grow0 = c0 * 16 + rsub, grow1 = c1 * 16 + rsub;
  const int klane = ((kq ^ sst) << 3);

  const _Float16* z0 = Zf + (size_t)(rowBase + grow0) * K + klane;
  const _Float16* z1 = Zf + (size_t)(rowBase + grow1) * K + klane;
  const _Float16* w0 = Wf + (size_t)(colBase + grow0) * K + klane;
  const _Float16* w1 = Wf + (size_t)(colBase + grow1) * K + klane;

  // drain the w2 loads so the counted-vmcnt schedule below is exact
  asm volatile("s_waitcnt vmcnt(0)" ::: "memory");

  // global step s in [0,64): vtile = s>>4, kstep = s&15
#define STAGE(buf, s)                                                         \
  do {                                                                        \
    const int koff_ = ((s) & 15) * 32;                                        \
    const size_t woff_ = (size_t)((s) >> 4) * 128 * K + koff_;                \
    GLOAD16(z0 + koff_, &smem[buf][c0 * 512]);                                \
    GLOAD16(w0 + woff_, &smem[buf][4096 + c0 * 512]);                         \
    GLOAD16(z1 + koff_, &smem[buf][c1 * 512]);                                \
    GLOAD16(w1 + woff_, &smem[buf][4096 + c1 * 512]);                         \
  } while (0)

  STAGE(0, 0);
  STAGE(1, 1);
  STAGE(2, 2);

#pragma unroll
  for (int vt = 0; vt < 4; ++vt) {
    f32x4 acc[4][4];
#pragma unroll
    for (int m = 0; m < 4; ++m)
#pragma unroll
      for (int n = 0; n < 4; ++n) acc[m][n] = f32x4{0.f, 0.f, 0.f, 0.f};

#pragma unroll
    for (int tt = 0; tt < 16; ++tt) {
      const int s = vt * 16 + tt;
      const int cur = s % 3;
      // complete only the oldest 4 loads (tile s); keep up to 8 in flight
      if (s <= 61)      asm volatile("s_waitcnt vmcnt(8)" ::: "memory");
      else if (s == 62) asm volatile("s_waitcnt vmcnt(4)" ::: "memory");
      else              asm volatile("s_waitcnt vmcnt(0)" ::: "memory");
      __builtin_amdgcn_s_barrier();  // all waves' tile-s loads now visible

      half8 a[4], b[4];
#pragma unroll
      for (int m = 0; m < 4; ++m) {
        const int off = (wr * 64 + m * 16 + tx) * 32 + ((g ^ srd) << 3);
        a[m] = *(const half8*)&smem[cur][off];
      }
#pragma unroll
      for (int n = 0; n < 4; ++n) {
        const int off = (wc * 64 + n * 16 + tx) * 32 + ((g ^ srd) << 3);
        b[n] = *(const half8*)&smem[cur][4096 + off];
      }
      __builtin_amdgcn_s_setprio(1);
#pragma unroll
      for (int m = 0; m < 4; ++m)
#pragma unroll
        for (int n = 0; n < 4; ++n)
          acc[m][n] = __builtin_amdgcn_mfma_f32_16x16x32_f16(a[m], b[n], acc[m][n], 0, 0, 0);
      __builtin_amdgcn_s_setprio(0);
      // all waves' ds_reads of buf[cur] complete before their barrier arrival
      // (MFMA data deps force lgkm waits) -> safe to re-stage buf[cur] after it
      __builtin_amdgcn_s_barrier();
      if (s <= 60) STAGE(cur, s + 3);
    }

    // fold this v-tile's scores into the running per-lane top-2 (no shuffles)
    float wv[4];
#pragma unroll
    for (int n = 0; n < 4; ++n) wv[n] = w2lds[vt * 128 + wc * 64 + n * 16 + tx];
#pragma unroll
    for (int m = 0; m < 4; ++m)
#pragma unroll
      for (int r = 0; r < 4; ++r)
#pragma unroll
        for (int n = 0; n < 4; ++n) {   // ascending col index -> strict < keeps smallest
          float sc = fmaf(-2.0f, acc[m][n][r], wv[n]);
          if (sc < tm1[m][r]) {
            tm2[m][r] = tm1[m][r]; tm1[m][r] = sc;
            ti1[m][r] = colBase + vt * 128 + wc * 64 + n * 16 + tx;
          } else {
            tm2[m][r] = fminf(tm2[m][r], sc);
          }
        }
  }
#undef STAGE

  // single epilogue: reduce 16 tx-lanes per row, write one half per (row, wc)
  const int hb = vtg * 2 + wc;
#pragma unroll
  for (int m = 0; m < 4; ++m) {
#pragma unroll
    for (int r = 0; r < 4; ++r) {
      float m1 = tm1[m][r], m2 = tm2[m][r];
      int i1 = ti1[m][r];
#pragma unroll
      for (int off = 1; off < 16; off <<= 1) {
        float om1 = __shfl_xor(m1, off, 64);
        float om2 = __shfl_xor(m2, off, 64);
        int oi = __shfl_xor(i1, off, 64);
        float nm2 = fminf(fmaxf(m1, om1), fminf(m2, om2));
        if (om1 < m1 || (om1 == m1 && oi < i1)) { m1 = om1; i1 = oi; }
        m2 = nm2;
      }
      if (tx == 0) {
        int row = rowBase + wr * 64 + m * 16 + g * 4 + r;
        size_t o = (size_t)row * 32 + hb;
        pm1[o] = m1; pm2[o] = m2; pi1[o] = i1;
      }
    }
  }
}

// -------------------- reduce 32 half partials per row -> argmin + flag
__global__ __launch_bounds__(256) void vq_reduce(
    const float* __restrict__ pm1, const float* __restrict__ pm2,
    const int* __restrict__ pi1,
    float* __restrict__ out_idx, int* __restrict__ ws_idx,
    int* __restrict__ flaglist, int* __restrict__ nflag) {
  int row = blockIdx.x * 4 + (threadIdx.x >> 6);
  int lane = threadIdx.x & 63;
  float a1 = 3.4e38f, a2 = 3.4e38f;
  int ai = 0x7fffffff;
  if (lane < 32) {
    size_t b = (size_t)row * 32 + lane;
    a1 = pm1[b]; a2 = pm2[b]; ai = pi1[b];
  }
#pragma unroll
  for (int off = 1; off < 32; off <<= 1) {
    float o1 = __shfl_xor(a1, off, 64);
    float o2 = __shfl_xor(a2, off, 64);
    int oi = __shfl_xor(ai, off, 64);
    float n2 = fminf(fmaxf(a1, o1), fminf(a2, o2));
    if (o1 < a1 || (o1 == a1 && oi < ai)) { a1 = o1; ai = oi; }
    a2 = n2;
  }
  if (lane == 0) {
    out_idx[row] = (float)ai;
    ws_idx[row] = ai;
    if (a2 - a1 < TAU) {
      int slot = atomicAdd(nflag, 1);
      flaglist[slot] = row;
    }
  }
}

// ---- pass 2: exact fp64 rescore, candidate-narrowed via per-half top-2.
// candidates: pi1[h] if pm1[h]<=m1+TAU; full 256-code half scan only if
// pm2[h]<=m1+TAU. Provably a superset of the exact argmin.
__global__ __launch_bounds__(256) void vq_fixup(
    const float* __restrict__ zr, const float* __restrict__ zi,
    const float* __restrict__ w, const double* __restrict__ w2d,
    const float* __restrict__ pm1, const float* __restrict__ pm2,
    const int* __restrict__ pi1,
    const int* __restrict__ flaglist, const int* __restrict__ nflag,
    float* __restrict__ out_idx, int* __restrict__ ws_idx) {
  __shared__ float zrow[K];
  __shared__ float redf[32];
  __shared__ int slist[32];
  __shared__ int hlist[32];
  __shared__ int ns_s, nh_s;
  __shared__ float thr_s;
  __shared__ double wmin[4];
  __shared__ int widx[4];
  const int tid = threadIdx.x;
  const int lane = tid & 63, wvq = tid >> 6;
  const int nf = *nflag;

  for (int f = blockIdx.x; f < nf; f += gridDim.x) {
    const int row = flaglist[f];
    __syncthreads();  // guard LDS reuse across grid-stride rows
    if (tid == 0) { ns_s = 0; nh_s = 0; }
    zrow[tid] = zr[(size_t)row * D + tid];
    zrow[256 + tid] = zi[(size_t)row * D + tid];
    if (tid < 32) redf[tid] = pm1[(size_t)row * 32 + tid];
    __syncthreads();
    if (tid == 0) {
      float m = redf[0];
      for (int h = 1; h < 32; ++h) m = fminf(m, redf[h]);
      thr_s = m + TAU;
    }
    __syncthreads();
    const float thr = thr_s;
    if (tid < 32) {
      if (pm2[(size_t)row * 32 + tid] <= thr) {
        hlist[atomicAdd(&nh_s, 1)] = tid;
      } else if (redf[tid] <= thr) {
        slist[atomicAdd(&ns_s, 1)] = pi1[(size_t)row * 32 + tid];
      }
    }
    __syncthreads();
    const int ns = ns_s, nh = nh_s;

    double best = 1e300;
    int bi = 0x7fffffff;

    // singles: 8 threads per candidate code (64 k-floats each)
    if (tid < ns * 8) {
      const int code = slist[tid >> 3], sub = tid & 7;
      const float4* w4 = (const float4*)(w + (size_t)code * K + sub * 64);
      const float4* z4 = (const float4*)(zrow + sub * 64);
      double d0 = 0.0, d1 = 0.0;
#pragma unroll
      for (int k4 = 0; k4 < 16; k4 += 2) {
        float4 a0 = w4[k4], b0 = z4[k4];
        float4 a1 = w4[k4 + 1], b1 = z4[k4 + 1];
        d0 = fma((double)a0.x, (double)b0.x, d0); d0 = fma((double)a0.y, (double)b0.y, d0);
        d0 = fma((double)a0.z, (double)b0.z, d0); d0 = fma((double)a0.w, (double)b0.w, d0);
        d1 = fma((double)a1.x, (double)b1.x, d1); d1 = fma((double)a1.y, (double)b1.y, d1);
        d1 = fma((double)a1.z, (double)b1.z, d1); d1 = fma((double)a1.w, (double)b1.w, d1);
      }
      double dot = d0 + d1;   // deterministic 8-lane combine
      dot += __shfl_xor(dot, 1, 64);
      dot += __shfl_xor(dot, 2, 64);
      dot += __shfl_xor(dot, 4, 64);
      if (sub == 0) {
        double d = w2d[code] - 2.0 * dot;
        if (d < best || (d == best && code < bi)) { best = d; bi = code; }
      }
    }

    // half scans: 256 codes per half, one per thread (full fp64 dot each)
    for (int hi = 0; hi < nh; ++hi) {
      const int h = hlist[hi];
      const int code = (h >> 1) * 512 + (tid >> 6) * 128 + (h & 1) * 64 + (tid & 63);
      const float4* w4 = (const float4*)(w + (size_t)code * K);
      const float4* z4 = (const float4*)zrow;
      double d0 = 0.0, d1 = 0.0, d2 = 0.0, d3 = 0.0;
      for (int k4 = 0; k4 < 128; k4 += 4) {
        float4 a0 = w4[k4], b0 = z4[k4];
        float4 a1 = w4[k4 + 1], b1 = z4[k4 + 1];
        float4 a2 = w4[k4 + 2], b2 = z4[k4 + 2];
        float4 a3 = w4[k4 + 3], b3 = z4[k4 + 3];
        d0 = fma((double)a0.x, (double)b0.x, d0); d0 = fma((double)a0.y, (double)b0.y, d0);
        d0 = fma((double)a0.z, (double)b0.z, d0); d0 = fma((double)a0.w, (double)b0.w, d0);
        d1 = fma((double)a1.x, (double)b1.x, d1); d1 = fma((double)a1.y, (double)b1.y, d1);
        d1 = fma((double)a1.z, (double)b1.z, d1); d1 = fma((double)a1.w, (double)b1.w, d1);
        d2 = fma((double)a2.x, (double)b2.x, d2); d2 = fma((double)a2.y, (double)b2.y, d2);
        d2 = fma((double)a2.z, (double)b2.z, d2); d2 = fma((double)a2.w, (double)b2.w, d2);
        d3 = fma((double)a3.x, (double)b3.x, d3); d3 = fma((double)a3.y, (double)b3.y, d3);
        d3 = fma((double)a3.z, (double)b3.z, d3); d3 = fma((double)a3.w, (double)b3.w, d3);
      }
      double d = w2d[code] - 2.0 * ((d0 + d1) + (d2 + d3));
      if (d < best || (d == best && code < bi)) { best = d; bi = code; }
    }

    // reduce 256 threads' (best, bi) -> 1 (order-independent comparator)
#pragma unroll
    for (int off = 1; off < 64; off <<= 1) {
      double ob = __shfl_xor(best, off, 64);
      int oi = __shfl_xor(bi, off, 64);
      if (ob < best || (ob == best && oi < bi)) { best = ob; bi = oi; }
    }
    if (lane == 0) { wmin[wvq] = best; widx[wvq] = bi; }
    __syncthreads();
    if (tid == 0) {
      double b0 = wmin[0]; int i0 = widx[0];
      for (int q = 1; q < 4; ++q)
        if (wmin[q] < b0 || (wmin[q] == b0 && widx[q] < i0)) { b0 = wmin[q]; i0 = widx[q]; }
      out_idx[row] = (float)i0;
      ws_idx[row] = i0;
    }
  }
}

// ---------------- gather z_q, write outputs 0/1, loss, histogram for entropy
__global__ __launch_bounds__(256) void vq_gather(
    const float* __restrict__ zr, const float* __restrict__ zi,
    const float* __restrict__ w, const int* __restrict__ ws_idx,
    float* __restrict__ out0, float* __restrict__ out1,
    float* __restrict__ out2, unsigned int* __restrict__ counts) {
  int row = blockIdx.x * 4 + (threadIdx.x >> 6);
  int lane = threadIdx.x & 63;
  int idx = ws_idx[row];
  const float4* wr = (const float4*)(w + (size_t)idx * K);
  float4 q0 = wr[lane];
  float4 q1 = wr[64 + lane];
  float4 a = ((const float4*)(zr + (size_t)row * D))[lane];
  float4 b = ((const float4*)(zi + (size_t)row * D))[lane];
  ((float4*)(out0 + (size_t)row * D))[lane] = q0;
  ((float4*)(out1 + (size_t)row * D))[lane] = q1;

  float s = 0.f, dx;
  dx = q0.x - a.x; s = fmaf(dx, dx, s);
  dx = q0.y - a.y; s = fmaf(dx, dx, s);
  dx = q0.z - a.z; s = fmaf(dx, dx, s);
  dx = q0.w - a.w; s = fmaf(dx, dx, s);
  dx = q1.x - b.x; s = fmaf(dx, dx, s);
  dx = q1.y - b.y; s = fmaf(dx, dx, s);
  dx = q1.z - b.z; s = fmaf(dx, dx, s);
  dx = q1.w - b.w; s = fmaf(dx, dx, s);
#pragma unroll
  for (int off = 1; off < 64; off <<= 1) s += __shfl_xor(s, off, 64);
  if (lane == 0) {
    out2[row] = s * (1.25f / 512.f);
    atomicAdd(counts + idx, 1u);
  }
}

// ------------------------------------------------------------------- entropy
__global__ __launch_bounds__(256) void vq_entropy(const unsigned int* __restrict__ counts,
                                                  float* __restrict__ out4) {
  __shared__ double sd[256];
  int tid = threadIdx.x;
  double e = 0.0;
  for (int v = tid; v < V; v += 256) {
    double p = (double)counts[v] * (1.0 / (double)N);
    e += p * log(p + 1e-10);
  }
  sd[tid] = e;
  __syncthreads();
  for (int s = 128; s > 0; s >>= 1) {
    if (tid < s) sd[tid] += sd[tid + s];
    __syncthreads();
  }
  if (tid == 0) *out4 = -(float)sd[0];
}

// ---------------------------------------------------------------------------
extern "C" void kernel_launch(void* const* d_in, const int* in_sizes, int n_in,
                              void* d_out, int out_size, void* d_ws, size_t ws_size,
                              hipStream_t stream) {
  const float* zr = (const float*)d_in[0];
  const float* zi = (const float*)d_in[1];
  const float* w = (const float*)d_in[2];

  float* out = (float*)d_out;
  float* out0 = out;                       // z_q real   (N*D)
  float* out1 = out + (size_t)N * D;       // z_q imag   (N*D)
  float* out2 = out + (size_t)2 * N * D;   // loss       (N)
  float* out3 = out2 + N;                  // indices    (N, as float)
  float* out4 = out3 + N;                  // entropy    (1)

  // top-2 partials live in the z_q output region; vq_gather overwrites it later
  float* pm1 = out;                              // N*32 floats = 2 MiB
  float* pm2 = out + (size_t)N * 32;             // 2 MiB
  int* pi1 = (int*)(out + (size_t)2 * N * 32);   // 2 MiB

  char* ws = (char*)d_ws;
  _Float16* Zf = (_Float16*)ws;                           // 16 MiB
  _Float16* Wf = (_Float16*)(ws + (((size_t)16) << 20));  // 8 MiB
  char* ws2 = ws + (((size_t)24) << 20);
  double* w2d = (double*)ws2;                          // 64 KiB
  float* w2f = (float*)(ws2 + 65536);                  // 32 KiB
  unsigned int* counts = (unsigned int*)(ws2 + 98304); // 32 KiB
  int* ws_idx = (int*)(ws2 + 131072);                  // 64 KiB
  int* flaglist = (int*)(ws2 + 196608);                // 64 KiB
  int* nflag = (int*)(ws2 + 262144);                   // 4 B

  (void)hipMemsetAsync(counts, 0, V * sizeof(unsigned int), stream);
  (void)hipMemsetAsync(nflag, 0, sizeof(int), stream);

  vq_cvt_z<<<N * 64 / 256, 256, 0, stream>>>(zr, zi, Zf);
  vq_cvt_w<<<V * 64 / 256, 256, 0, stream>>>(w, Wf);
  vq_w2<<<V / 4, 256, 0, stream>>>(w, w2d, w2f);
  vq_pass1<<<(N / 128) * (V / 512), 256, 0, stream>>>(Zf, Wf, w2f, pm1, pm2, pi1);
  vq_reduce<<<N / 4, 256, 0, stream>>>(pm1, pm2, pi1, out3, ws_idx, flaglist, nflag);
  vq_fixup<<<4096, 256, 0, stream>>>(zr, zi, w, w2d, pm1, pm2, pi1, flaglist, nflag,
                                     out3, ws_idx);
  vq_gather<<<N / 4, 256, 0, stream>>>(zr, zi, w, ws_idx, out0, out1, out2, counts);
  vq_entropy<<<1, 256, 0, stream>>>(counts, out4);
}

// Round 10
// 293.491 us; speedup vs baseline: 1.3751x; 1.3751x over previous
//
#include <hip/hip_runtime.h>
#include <cmath>

typedef _Float16 half8 __attribute__((ext_vector_type(8)));
typedef float f32x4 __attribute__((ext_vector_type(4)));

constexpr int N = 16384;   // rows
constexpr int D = 256;     // half feature dim
constexpr int K = 512;     // 2D
constexpr int V = 8192;    // codebook size
// fp16 score error: std ~ 4.9e-4; 12-sigma + accum slack -> per-code bound
// B ~ 6e-3. TAU >= 2B keeps the fixup set a superset of the exact argmin.
constexpr float TAU = 0.015f;

#define GLOAD16(g, l) __builtin_amdgcn_global_load_lds(                     \
    (const __attribute__((address_space(1))) void*)(g),                    \
    (__attribute__((address_space(3))) void*)(l), 16, 0, 0)

// --------------------------- convert z (concat real|imag) to fp16 [N][K]
__global__ __launch_bounds__(256) void vq_cvt_z(
    const float* __restrict__ zr, const float* __restrict__ zi,
    _Float16* __restrict__ Zf) {
  int t = blockIdx.x * 256 + threadIdx.x;   // [0, N*64)
  int n = t >> 6, c8 = t & 63, k = c8 * 8;
  const float* src = (k < D) ? zr + (size_t)n * D + k : zi + (size_t)n * D + (k - D);
  float4 a = *(const float4*)src;
  float4 b = *(const float4*)(src + 4);
  half8 h;
  h[0] = (_Float16)a.x; h[1] = (_Float16)a.y; h[2] = (_Float16)a.z; h[3] = (_Float16)a.w;
  h[4] = (_Float16)b.x; h[5] = (_Float16)b.y; h[6] = (_Float16)b.z; h[7] = (_Float16)b.w;
  *(half8*)&Zf[(size_t)n * K + k] = h;
}

// ------------------------------------------------------ convert w to fp16
__global__ __launch_bounds__(256) void vq_cvt_w(
    const float* __restrict__ w, _Float16* __restrict__ Wf) {
  int t = blockIdx.x * 256 + threadIdx.x;   // [0, V*64)
  int vrow = t >> 6, c8 = t & 63, k = c8 * 8;
  const float* src = w + (size_t)vrow * K + k;
  float4 a = *(const float4*)src;
  float4 b = *(const float4*)(src + 4);
  half8 h;
  h[0] = (_Float16)a.x; h[1] = (_Float16)a.y; h[2] = (_Float16)a.z; h[3] = (_Float16)a.w;
  h[4] = (_Float16)b.x; h[5] = (_Float16)b.y; h[6] = (_Float16)b.z; h[7] = (_Float16)b.w;
  *(half8*)&Wf[(size_t)vrow * K + k] = h;
}

// ---------------------------------------------------------------- w2 = ||w||^2
__global__ __launch_bounds__(256) void vq_w2(const float* __restrict__ w,
                                             double* __restrict__ w2d,
                                             float* __restrict__ w2f) {
  int v = blockIdx.x * 4 + (threadIdx.x >> 6);
  int lane = threadIdx.x & 63;
  const float4* wr = (const float4*)(w + (size_t)v * K);
  float4 a = wr[lane];
  float4 b = wr[64 + lane];
  double s = (double)a.x * a.x + (double)a.y * a.y + (double)a.z * a.z + (double)a.w * a.w +
             (double)b.x * b.x + (double)b.y * b.y + (double)b.z * b.z + (double)b.w * b.w;
#pragma unroll
  for (int off = 1; off < 64; off <<= 1) s += __shfl_xor(s, off, 64);
  if (lane == 0) { w2d[v] = s; w2f[v] = (float)s; }
}

// ------ pass 1: fp16 MFMA GEMM, 256x128 tile, 512 thr = 8 waves (4 row x 2 col),
// 3-buffer LDS rotation, counted vmcnt + raw s_barrier (R8-verified skeleton).
// grid 4096: vt = bid & 63 (V/128), nt = bid >> 6 (N/256).
__global__ __launch_bounds__(512) void vq_pass1(
    const _Float16* __restrict__ Zf, const _Float16* __restrict__ Wf,
    const float* __restrict__ w2f,
    float* __restrict__ pm1, float* __restrict__ pm2, int* __restrict__ pi1) {
  // per buffer: Z [256][32] (16 KiB) + W [128][32] (8 KiB); 3 bufs = 72 KiB
  __shared__ __align__(16) unsigned short smem[3][12288];

  const int tid = threadIdx.x;
  const int w = tid >> 6, lane = tid & 63;     // 8 waves
  const int wr = w >> 1, wc = w & 1;           // wave tile: rows wr*64, cols wc*64
  const int tx = lane & 15, g = lane >> 4;
  const int rsub = lane >> 2, kq = lane & 3;   // staging row-sub / k-quad
  const int vt = blockIdx.x & 63, nt = blockIdx.x >> 6;
  const int rowBase = nt * 256, colBase = vt * 128;

  f32x4 acc[4][4];
#pragma unroll
  for (int m = 0; m < 4; ++m)
#pragma unroll
    for (int n = 0; n < 4; ++n) acc[m][n] = f32x4{0.f, 0.f, 0.f, 0.f};

  const int sst = (rsub >> 1) & 3;  // stage-side swizzle (pre-swizzled global src)
  const int srd = (tx >> 1) & 3;    // read-side swizzle (same involution)

  // staging: Z = 16 chunks of 16 rows (wave w stages 2w, 2w+1); W = 8 chunks (wave w)
  const int zc0 = 2 * w, zc1 = 2 * w + 1;
  const int zrow0 = zc0 * 16 + rsub, zrow1 = zc1 * 16 + rsub;
  const int wrow = w * 16 + rsub;
  const int klane = ((kq ^ sst) << 3);

  const _Float16* z0 = Zf + (size_t)(rowBase + zrow0) * K + klane;
  const _Float16* z1 = Zf + (size_t)(rowBase + zrow1) * K + klane;
  const _Float16* w0 = Wf + (size_t)(colBase + wrow) * K + klane;

#define STAGE(buf, koff)                                                      \
  do {                                                                        \
    GLOAD16(z0 + (koff), &smem[buf][zc0 * 512]);                              \
    GLOAD16(z1 + (koff), &smem[buf][zc1 * 512]);                              \
    GLOAD16(w0 + (koff), &smem[buf][8192 + w * 512]);                         \
  } while (0)

  STAGE(0, 0);     // tile 0: 3 loads in flight
  STAGE(1, 32);    // tile 1: 6
  STAGE(2, 64);    // tile 2: 9

#pragma unroll
  for (int t = 0; t < 16; ++t) {
    const int cur = t % 3;
    // complete only the oldest 3 loads (tile t); keep up to 6 in flight
    if (t <= 13)      asm volatile("s_waitcnt vmcnt(6)" ::: "memory");
    else if (t == 14) asm volatile("s_waitcnt vmcnt(3)" ::: "memory");
    else              asm volatile("s_waitcnt vmcnt(0)" ::: "memory");
    __builtin_amdgcn_s_barrier();  // all waves' tile-t loads now visible

    half8 a[4], b[4];
#pragma unroll
    for (int m = 0; m < 4; ++m) {
      const int off = (wr * 64 + m * 16 + tx) * 32 + ((g ^ srd) << 3);
      a[m] = *(const half8*)&smem[cur][off];
    }
#pragma unroll
    for (int n = 0; n < 4; ++n) {
      const int off = 8192 + (wc * 64 + n * 16 + tx) * 32 + ((g ^ srd) << 3);
      b[n] = *(const half8*)&smem[cur][off];
    }
    __builtin_amdgcn_s_setprio(1);
#pragma unroll
    for (int m = 0; m < 4; ++m)
#pragma unroll
      for (int n = 0; n < 4; ++n)
        acc[m][n] = __builtin_amdgcn_mfma_f32_16x16x32_f16(a[m], b[n], acc[m][n], 0, 0, 0);
    __builtin_amdgcn_s_setprio(0);
    // all waves' ds_reads of buf[cur] complete before their barrier arrival
    // (MFMA data deps force lgkm waits) -> safe to re-stage buf[cur] after it
    __builtin_amdgcn_s_barrier();
    if (t <= 12) STAGE(cur, (t + 3) * 32);
  }
#undef STAGE

  // epilogue: scores = w2 - 2*dot, per-row top-2 over this wave's 64 cols
  float wcol[4];
#pragma unroll
  for (int n = 0; n < 4; ++n) wcol[n] = w2f[colBase + wc * 64 + n * 16 + tx];
  const int cb = vt * 2 + wc;   // 128 column-halves of 64 codes

#pragma unroll
  for (int m = 0; m < 4; ++m) {
#pragma unroll
    for (int r = 0; r < 4; ++r) {
      float m1 = 3.4e38f, m2 = 3.4e38f;
      int i1 = 0;
#pragma unroll
      for (int n = 0; n < 4; ++n) {   // ascending v -> ties keep smallest index
        float s = fmaf(-2.0f, acc[m][n][r], wcol[n]);
        if (s < m1) { m2 = m1; m1 = s; i1 = colBase + wc * 64 + n * 16 + tx; }
        else m2 = fminf(m2, s);
      }
#pragma unroll
      for (int off = 1; off < 16; off <<= 1) {  // reduce 16 lanes sharing a row
        float om1 = __shfl_xor(m1, off, 64);
        float om2 = __shfl_xor(m2, off, 64);
        int oi = __shfl_xor(i1, off, 64);
        float nm2 = fminf(fmaxf(m1, om1), fminf(m2, om2));
        if (om1 < m1 || (om1 == m1 && oi < i1)) { m1 = om1; i1 = oi; }
        m2 = nm2;
      }
      if (tx == 0) {
        int row = rowBase + wr * 64 + m * 16 + g * 4 + r;
        size_t o = (size_t)row * 128 + cb;
        pm1[o] = m1; pm2[o] = m2; pi1[o] = i1;
      }
    }
  }
}

// ------------------- reduce 128 column-half partials per row -> argmin + flag
__global__ __launch_bounds__(256) void vq_reduce(
    const float* __restrict__ pm1, const float* __restrict__ pm2,
    const int* __restrict__ pi1,
    float* __restrict__ out_idx, int* __restrict__ ws_idx,
    int* __restrict__ flaglist, int* __restrict__ nflag) {
  int row = blockIdx.x * 4 + (threadIdx.x >> 6);
  int lane = threadIdx.x & 63;
  size_t b = (size_t)row * 128;
  float a1 = pm1[b + lane], a2 = pm2[b + lane];
  int ai = pi1[b + lane];
  float b1 = pm1[b + lane + 64], b2 = pm2[b + lane + 64];
  int bi = pi1[b + lane + 64];
  float nm2 = fminf(fmaxf(a1, b1), fminf(a2, b2));
  if (b1 < a1 || (b1 == a1 && bi < ai)) { a1 = b1; ai = bi; }
  a2 = nm2;
#pragma unroll
  for (int off = 1; off < 64; off <<= 1) {
    float o1 = __shfl_xor(a1, off, 64);
    float o2 = __shfl_xor(a2, off, 64);
    int oi = __shfl_xor(ai, off, 64);
    float n2 = fminf(fmaxf(a1, o1), fminf(a2, o2));
    if (o1 < a1 || (o1 == a1 && oi < ai)) { a1 = o1; ai = oi; }
    a2 = n2;
  }
  if (lane == 0) {
    out_idx[row] = (float)ai;
    ws_idx[row] = ai;
    if (a2 - a1 < TAU) {
      int slot = atomicAdd(nflag, 1);
      flaglist[slot] = row;
    }
  }
}

// ---- pass 2: exact fp64 rescore, candidate-narrowed via per-half top-2.
// candidates: pi1[h] if pm1[h]<=m1+TAU; full 64-code half scan only if
// pm2[h]<=m1+TAU. Provably a superset of the exact argmin.
__global__ __launch_bounds__(256) void vq_fixup(
    const float* __restrict__ zr, const float* __restrict__ zi,
    const float* __restrict__ w, const double* __restrict__ w2d,
    const float* __restrict__ pm1, const float* __restrict__ pm2,
    const int* __restrict__ pi1,
    const int* __restrict__ flaglist, const int* __restrict__ nflag,
    float* __restrict__ out_idx, int* __restrict__ ws_idx) {
  __shared__ float zrow[K];
  __shared__ float redf[128];
  __shared__ int slist[128];
  __shared__ int hlist[128];
  __shared__ int ns_s, nh_s;
  __shared__ float thr_s;
  __shared__ double wmin[4];
  __shared__ int widx[4];
  const int tid = threadIdx.x;
  const int lane = tid & 63, wvq = tid >> 6;
  const int nf = *nflag;

  for (int f = blockIdx.x; f < nf; f += gridDim.x) {
    const int row = flaglist[f];
    __syncthreads();  // guard LDS reuse across grid-stride rows
    if (tid == 0) { ns_s = 0; nh_s = 0; }
    zrow[tid] = zr[(size_t)row * D + tid];
    zrow[256 + tid] = zi[(size_t)row * D + tid];
    if (tid < 128) redf[tid] = pm1[(size_t)row * 128 + tid];
    __syncthreads();
    if (wvq == 0) {   // wave 0: min over the 128 half-minima (redf kept intact)
      float v = fminf(redf[lane], redf[lane + 64]);
#pragma unroll
      for (int off = 1; off < 64; off <<= 1) v = fminf(v, __shfl_xor(v, off, 64));
      if (lane == 0) thr_s = v + TAU;
    }
    __syncthreads();
    const float thr = thr_s;
    if (tid < 128) {
      if (pm2[(size_t)row * 128 + tid] <= thr) {
        hlist[atomicAdd(&nh_s, 1)] = tid;
      } else if (redf[tid] <= thr) {
        slist[atomicAdd(&ns_s, 1)] = pi1[(size_t)row * 128 + tid];
      }
    }
    __syncthreads();
    const int ns = ns_s, nh = nh_s;

    double best = 1e300;
    int bi = 0x7fffffff;

    // singles: 8 threads per candidate code (64 k-floats each)
    for (int ci = tid >> 3; ci < ns; ci += 32) {
      const int code = slist[ci], sub = tid & 7;
      const float4* w4 = (const float4*)(w + (size_t)code * K + sub * 64);
      const float4* z4 = (const float4*)(zrow + sub * 64);
      double d0 = 0.0, d1 = 0.0;
#pragma unroll
      for (int k4 = 0; k4 < 16; k4 += 2) {
        float4 a0 = w4[k4], b0 = z4[k4];
        float4 a1 = w4[k4 + 1], b1 = z4[k4 + 1];
        d0 = fma((double)a0.x, (double)b0.x, d0); d0 = fma((double)a0.y, (double)b0.y, d0);
        d0 = fma((double)a0.z, (double)b0.z, d0); d0 = fma((double)a0.w, (double)b0.w, d0);
        d1 = fma((double)a1.x, (double)b1.x, d1); d1 = fma((double)a1.y, (double)b1.y, d1);
        d1 = fma((double)a1.z, (double)b1.z, d1); d1 = fma((double)a1.w, (double)b1.w, d1);
      }
      double dot = d0 + d1;   // deterministic 8-lane combine
      dot += __shfl_xor(dot, 1, 64);
      dot += __shfl_xor(dot, 2, 64);
      dot += __shfl_xor(dot, 4, 64);
      if (sub == 0) {
        double d = w2d[code] - 2.0 * dot;
        if (d < best || (d == best && code < bi)) { best = d; bi = code; }
      }
    }

    // half scans: one wave per half, one code per lane (full fp64 dot each)
    for (int hi = wvq; hi < nh; hi += 4) {
      const int code = hlist[hi] * 64 + lane;
      const float4* w4 = (const float4*)(w + (size_t)code * K);
      const float4* z4 = (const float4*)zrow;
      double d0 = 0.0, d1 = 0.0, d2 = 0.0, d3 = 0.0;
      for (int k4 = 0; k4 < 128; k4 += 4) {
        float4 a0 = w4[k4], b0 = z4[k4];
        float4 a1 = w4[k4 + 1], b1 = z4[k4 + 1];
        float4 a2 = w4[k4 + 2], b2 = z4[k4 + 2];
        float4 a3 = w4[k4 + 3], b3 = z4[k4 + 3];
        d0 = fma((double)a0.x, (double)b0.x, d0); d0 = fma((double)a0.y, (double)b0.y, d0);
        d0 = fma((double)a0.z, (double)b0.z, d0); d0 = fma((double)a0.w, (double)b0.w, d0);
        d1 = fma((double)a1.x, (double)b1.x, d1); d1 = fma((double)a1.y, (double)b1.y, d1);
        d1 = fma((double)a1.z, (double)b1.z, d1); d1 = fma((double)a1.w, (double)b1.w, d1);
        d2 = fma((double)a2.x, (double)b2.x, d2); d2 = fma((double)a2.y, (double)b2.y, d2);
        d2 = fma((double)a2.z, (double)b2.z, d2); d2 = fma((double)a2.w, (double)b2.w, d2);
        d3 = fma((double)a3.x, (double)b3.x, d3); d3 = fma((double)a3.y, (double)b3.y, d3);
        d3 = fma((double)a3.z, (double)b3.z, d3); d3 = fma((double)a3.w, (double)b3.w, d3);
      }
      double d = w2d[code] - 2.0 * ((d0 + d1) + (d2 + d3));
      if (d < best || (d == best && code < bi)) { best = d; bi = code; }
    }

    // reduce 256 threads' (best, bi) -> 1 (order-independent comparator)
#pragma unroll
    for (int off = 1; off < 64; off <<= 1) {
      double ob = __shfl_xor(best, off, 64);
      int oi = __shfl_xor(bi, off, 64);
      if (ob < best || (ob == best && oi < bi)) { best = ob; bi = oi; }
    }
    if (lane == 0) { wmin[wvq] = best; widx[wvq] = bi; }
    __syncthreads();
    if (tid == 0) {
      double b0 = wmin[0]; int i0 = widx[0];
      for (int q = 1; q < 4; ++q)
        if (wmin[q] < b0 || (wmin[q] == b0 && widx[q] < i0)) { b0 = wmin[q]; i0 = widx[q]; }
      out_idx[row] = (float)i0;
      ws_idx[row] = i0;
    }
  }
}

// ---------------- gather z_q, write outputs 0/1, loss, histogram for entropy
__global__ __launch_bounds__(256) void vq_gather(
    const float* __restrict__ zr, const float* __restrict__ zi,
    const float* __restrict__ w, const int* __restrict__ ws_idx,
    float* __restrict__ out0, float* __restrict__ out1,
    float* __restrict__ out2, unsigned int* __restrict__ counts) {
  int row = blockIdx.x * 4 + (threadIdx.x >> 6);
  int lane = threadIdx.x & 63;
  int idx = ws_idx[row];
  const float4* wr = (const float4*)(w + (size_t)idx * K);
  float4 q0 = wr[lane];
  float4 q1 = wr[64 + lane];
  float4 a = ((const float4*)(zr + (size_t)row * D))[lane];
  float4 b = ((const float4*)(zi + (size_t)row * D))[lane];
  ((float4*)(out0 + (size_t)row * D))[lane] = q0;
  ((float4*)(out1 + (size_t)row * D))[lane] = q1;

  float s = 0.f, dx;
  dx = q0.x - a.x; s = fmaf(dx, dx, s);
  dx = q0.y - a.y; s = fmaf(dx, dx, s);
  dx = q0.z - a.z; s = fmaf(dx, dx, s);
  dx = q0.w - a.w; s = fmaf(dx, dx, s);
  dx = q1.x - b.x; s = fmaf(dx, dx, s);
  dx = q1.y - b.y; s = fmaf(dx, dx, s);
  dx = q1.z - b.z; s = fmaf(dx, dx, s);
  dx = q1.w - b.w; s = fmaf(dx, dx, s);
#pragma unroll
  for (int off = 1; off < 64; off <<= 1) s += __shfl_xor(s, off, 64);
  if (lane == 0) {
    out2[row] = s * (1.25f / 512.f);
    atomicAdd(counts + idx, 1u);
  }
}

// ------------------------------------------------------------------- entropy
__global__ __launch_bounds__(256) void vq_entropy(const unsigned int* __restrict__ counts,
                                                  float* __restrict__ out4) {
  __shared__ double sd[256];
  int tid = threadIdx.x;
  double e = 0.0;
  for (int v = tid; v < V; v += 256) {
    double p = (double)counts[v] * (1.0 / (double)N);
    e += p * log(p + 1e-10);
  }
  sd[tid] = e;
  __syncthreads();
  for (int s = 128; s > 0; s >>= 1) {
    if (tid < s) sd[tid] += sd[tid + s];
    __syncthreads();
  }
  if (tid == 0) *out4 = -(float)sd[0];
}

// ---------------------------------------------------------------------------
extern "C" void kernel_launch(void* const* d_in, const int* in_sizes, int n_in,
                              void* d_out, int out_size, void* d_ws, size_t ws_size,
                              hipStream_t stream) {
  const float* zr = (const float*)d_in[0];
  const float* zi = (const float*)d_in[1];
  const float* w = (const float*)d_in[2];

  float* out = (float*)d_out;
  float* out0 = out;                       // z_q real   (N*D)
  float* out1 = out + (size_t)N * D;       // z_q imag   (N*D)
  float* out2 = out + (size_t)2 * N * D;   // loss       (N)
  float* out3 = out2 + N;                  // indices    (N, as float)
  float* out4 = out3 + N;                  // entropy    (1)

  // top-2 partials live in the z_q output region; vq_gather overwrites it later
  float* pm1 = out;                              // N*128 floats = 8 MiB
  float* pm2 = out + (size_t)N * 128;            // 8 MiB
  int* pi1 = (int*)(out + (size_t)2 * N * 128);  // 8 MiB

  char* ws = (char*)d_ws;
  _Float16* Zf = (_Float16*)ws;                           // 16 MiB
  _Float16* Wf = (_Float16*)(ws + (((size_t)16) << 20));  // 8 MiB
  char* ws2 = ws + (((size_t)24) << 20);
  double* w2d = (double*)ws2;                          // 64 KiB
  float* w2f = (float*)(ws2 + 65536);                  // 32 KiB
  unsigned int* counts = (unsigned int*)(ws2 + 98304); // 32 KiB
  int* ws_idx = (int*)(ws2 + 131072);                  // 64 KiB
  int* flaglist = (int*)(ws2 + 196608);                // 64 KiB
  int* nflag = (int*)(ws2 + 262144);                   // 4 B

  (void)hipMemsetAsync(counts, 0, V * sizeof(unsigned int), stream);
  (void)hipMemsetAsync(nflag, 0, sizeof(int), stream);

  vq_cvt_z<<<N * 64 / 256, 256, 0, stream>>>(zr, zi, Zf);
  vq_cvt_w<<<V * 64 / 256, 256, 0, stream>>>(w, Wf);
  vq_w2<<<V / 4, 256, 0, stream>>>(w, w2d, w2f);
  vq_pass1<<<(N / 256) * (V / 128), 512, 0, stream>>>(Zf, Wf, w2f, pm1, pm2, pi1);
  vq_reduce<<<N / 4, 256, 0, stream>>>(pm1, pm2, pi1, out3, ws_idx, flaglist, nflag);
  vq_fixup<<<4096, 256, 0, stream>>>(zr, zi, w, w2d, pm1, pm2, pi1, flaglist, nflag,
                                     out3, ws_idx);
  vq_gather<<<N / 4, 256, 0, stream>>>(zr, zi, w, ws_idx, out0, out1, out2, counts);
  vq_entropy<<<1, 256, 0, stream>>>(counts, out4);
}